// Round 1
// baseline (5258.292 us; speedup 1.0000x reference)
//
#include <hip/hip_runtime.h>
#include <hip/hip_bf16.h>
#include <math.h>

#define L_CNT 20000
#define U_CNT 2048
#define M_CNT 3
#define D_CNT 256
#define T_CNT 5
#define K_OUT 8
#define KC    16
#define SLAB  128
#define NSLAB (U_CNT/SLAB)
#define TU 32
#define TL 128
#define KB 64

// -------- helpers --------
__device__ inline double dshfl_xor(double v, int m){
    long long x = __double_as_longlong(v);
    int lo = (int)(x & 0xffffffffLL);
    int hi = (int)(((unsigned long long)x) >> 32);
    lo = __shfl_xor(lo, m, 64);
    hi = __shfl_xor(hi, m, 64);
    return __longlong_as_double(((long long)hi << 32) | (long long)(unsigned int)lo);
}

// -------- K0: softmax weights (f32, fast pass only) --------
__global__ void weights_kernel(const float* __restrict__ logits, float* __restrict__ w32){
    int t = threadIdx.x;
    if (t < T_CNT){
        float a = logits[t*M_CNT+0], b = logits[t*M_CNT+1], c = logits[t*M_CNT+2];
        float mx = fmaxf(a, fmaxf(b, c));
        float e0 = expf(a-mx), e1 = expf(b-mx), e2 = expf(c-mx);
        float s = e0+e1+e2;
        w32[t*M_CNT+0] = e0/s; w32[t*M_CNT+1] = e1/s; w32[t*M_CNT+2] = e2/s;
    }
}

// -------- K1: inverse norms (f32, fast pass only) --------
__global__ __launch_bounds__(256) void norm_kernel(const float* __restrict__ lab,
    const float* __restrict__ unl, float* __restrict__ labInv, float* __restrict__ unlInv){
    const int NROW = L_CNT*M_CNT + U_CNT*M_CNT;   // 66144
    int row = blockIdx.x*4 + (threadIdx.x >> 6);
    int lane = threadIdx.x & 63;
    if (row >= NROW) return;
    const float* p = (row < L_CNT*M_CNT) ? (lab + (size_t)row*D_CNT)
                                         : (unl + (size_t)(row - L_CNT*M_CNT)*D_CNT);
    float4 a = ((const float4*)p)[lane];
    float s = a.x*a.x + a.y*a.y + a.z*a.z + a.w*a.w;
#pragma unroll
    for (int m=1;m<64;m<<=1) s += __shfl_xor(s, m, 64);
    float inv = 1.0f/(sqrtf(s) + 1e-8f);
    if (lane == 0){
        if (row < L_CNT*M_CNT) labInv[row] = inv;
        else unlInv[row - L_CNT*M_CNT] = inv;
    }
}

// -------- K2: fused modality-GEMM + trait combine (f32 fast pass) --------
// grid: (ceil(L/TL)=157, SLAB/TU=4); block 256. Writes slab[u_local][t][l].
__global__ __launch_bounds__(256) void sim_kernel(const float* __restrict__ lab,
    const float* __restrict__ unl, const float* __restrict__ labInv,
    const float* __restrict__ unlInv, const float* __restrict__ w32,
    float* __restrict__ slabp, int s)
{
    __shared__ float sU[TU][KB+4];
    __shared__ float sL[TL][KB+4];
    const int tid = threadIdx.x;
    const int l0 = blockIdx.x * TL;
    const int uB = blockIdx.y * TU;          // within slab
    const int gu0 = s*SLAB + uB;             // global query base
    const int tu = tid >> 5;                 // 0..7 -> 4 u rows
    const int tl = tid & 31;                 // 0..31 -> 4 l cols

    float w[T_CNT][M_CNT];
#pragma unroll
    for (int t=0;t<T_CNT;t++)
#pragma unroll
        for (int m=0;m<M_CNT;m++) w[t][m] = w32[t*M_CNT+m];

    float comb[T_CNT][4][4] = {};

    for (int m=0;m<M_CNT;m++){
        float acc[4][4] = {};
        for (int kb=0;kb<D_CNT;kb+=KB){
            __syncthreads();
            // stage unl tile: 32 rows x 64 cols = 512 float4
#pragma unroll
            for (int r=0;r<2;r++){
                int id = tid + r*256;
                int row = id >> 4;
                int c4 = id & 15;
                float4 v = *(const float4*)&unl[ (((size_t)(gu0+row))*M_CNT + m)*D_CNT + kb + c4*4 ];
                float sc = unlInv[(gu0+row)*M_CNT + m];
                v.x*=sc; v.y*=sc; v.z*=sc; v.w*=sc;
                *(float4*)&sU[row][c4*4] = v;
            }
            // stage lab tile: 128 rows x 64 cols = 2048 float4
#pragma unroll
            for (int r=0;r<8;r++){
                int id = tid + r*256;
                int row = id >> 4;
                int c4 = id & 15;
                int lrow = l0 + row;
                float4 v = make_float4(0.f,0.f,0.f,0.f);
                float sc = 0.f;
                if (lrow < L_CNT){
                    v = *(const float4*)&lab[ (((size_t)lrow)*M_CNT + m)*D_CNT + kb + c4*4 ];
                    sc = labInv[lrow*M_CNT + m];
                }
                v.x*=sc; v.y*=sc; v.z*=sc; v.w*=sc;
                *(float4*)&sL[row][c4*4] = v;
            }
            __syncthreads();
#pragma unroll 4
            for (int dd=0;dd<KB;dd+=4){
                float4 av[4], bvv[4];
#pragma unroll
                for (int i=0;i<4;i++) av[i] = *(const float4*)&sU[tu*4+i][dd];
#pragma unroll
                for (int j=0;j<4;j++) bvv[j] = *(const float4*)&sL[tl*4+j][dd];
#pragma unroll
                for (int i=0;i<4;i++)
#pragma unroll
                    for (int j=0;j<4;j++){
                        acc[i][j] += av[i].x*bvv[j].x;
                        acc[i][j] += av[i].y*bvv[j].y;
                        acc[i][j] += av[i].z*bvv[j].z;
                        acc[i][j] += av[i].w*bvv[j].w;
                    }
            }
        }
#pragma unroll
        for (int t=0;t<T_CNT;t++)
#pragma unroll
            for (int i=0;i<4;i++)
#pragma unroll
                for (int j=0;j<4;j++) comb[t][i][j] += w[t][m]*acc[i][j];
    }

    // store combined sims
#pragma unroll
    for (int t=0;t<T_CNT;t++)
#pragma unroll
        for (int i=0;i<4;i++){
            int ul = uB + tu*4 + i;
            int l  = l0 + tl*4;
            size_t base = ((size_t)ul*T_CNT + t)*L_CNT + l;
            if (l + 3 < L_CNT){
                *(float4*)&slabp[base] = make_float4(comb[t][i][0], comb[t][i][1], comb[t][i][2], comb[t][i][3]);
            } else {
#pragma unroll
                for (int j=0;j<4;j++) if (l+j < L_CNT) slabp[base+j] = comb[t][i][j];
            }
        }
}

// -------- K3: exact top-KC per (u,t) --------
// grid: (SLAB, T); block 256. Per-thread sorted top-16 + 16-round block merge.
__global__ __launch_bounds__(256) void select_kernel(const float* __restrict__ slabp,
    float* __restrict__ candVal, int* __restrict__ candIdx, int s)
{
    const int ul = blockIdx.x;
    const int t  = blockIdx.y;
    const int gu = s*SLAB + ul;
    const float* row = slabp + ((size_t)ul*T_CNT + t)*L_CNT;
    const int tid = threadIdx.x;

    float bv[KC]; int bi[KC];
#pragma unroll
    for (int i=0;i<KC;i++){ bv[i] = -INFINITY; bi[i] = 0x7fffffff; }

    for (int l = tid; l < L_CNT; l += 256){
        float v = row[l];
        if (v > bv[KC-1] || (v == bv[KC-1] && l < bi[KC-1])){
            int rank = 0;
#pragma unroll
            for (int p=0;p<KC;p++) rank += ((bv[p] > v) || (bv[p] == v && bi[p] < l)) ? 1 : 0;
#pragma unroll
            for (int p=KC-1;p>0;--p){ if (p > rank){ bv[p]=bv[p-1]; bi[p]=bi[p-1]; } }
#pragma unroll
            for (int p=0;p<KC;p++){ if (p == rank){ bv[p]=v; bi[p]=l; } }
        }
    }

    __shared__ float wvs[4]; __shared__ int wis[4]; __shared__ int wts[4];
    __shared__ int sbt;
    const int lane = tid & 63, wid = tid >> 6;

    for (int k=0;k<KC;k++){
        float cv = bv[0]; int ci = bi[0]; int ct = tid;
#pragma unroll
        for (int mm=1;mm<64;mm<<=1){
            float ov = __shfl_xor(cv, mm, 64);
            int oi = __shfl_xor(ci, mm, 64);
            int ot = __shfl_xor(ct, mm, 64);
            if (ov > cv || (ov == cv && (oi < ci || (oi == ci && ot < ct)))){ cv=ov; ci=oi; ct=ot; }
        }
        if (lane == 0){ wvs[wid]=cv; wis[wid]=ci; wts[wid]=ct; }
        __syncthreads();
        if (tid == 0){
            float fv = wvs[0]; int fi = wis[0]; int ft = wts[0];
#pragma unroll
            for (int q=1;q<4;q++){
                float ov=wvs[q]; int oi=wis[q]; int ot=wts[q];
                if (ov > fv || (ov == fv && (oi < fi || (oi == fi && ot < ft)))){ fv=ov; fi=oi; ft=ot; }
            }
            size_t cb = ((size_t)gu*T_CNT + t)*KC + k;
            candVal[cb] = fv; candIdx[cb] = fi;
            sbt = ft;
        }
        __syncthreads();
        if (tid == sbt){
#pragma unroll
            for (int p=0;p<KC-1;p++){ bv[p]=bv[p+1]; bi[p]=bi[p+1]; }
            bv[KC-1] = -INFINITY; bi[KC-1] = 0x7fffffff;
        }
        __syncthreads();
    }
}

// -------- K4: f64 rescore of 16 candidates + traits/index outputs --------
// grid: (U, T); block 64 (one wave).
__global__ __launch_bounds__(64) void rescore_kernel(
    const float* __restrict__ lab, const float* __restrict__ unl,
    const float* __restrict__ traits, const float* __restrict__ logits,
    const int* __restrict__ candIdx,
    float* __restrict__ outTraits, float* __restrict__ outIdx, int* __restrict__ finalIdx)
{
    const int u = blockIdx.x, t = blockIdx.y, lane = threadIdx.x;

    // f64 softmax weights for trait t
    double lg[3];
#pragma unroll
    for (int m=0;m<3;m++) lg[m] = (double)logits[t*M_CNT+m];
    double mx = fmax(lg[0], fmax(lg[1], lg[2]));
    double e0 = exp(lg[0]-mx), e1 = exp(lg[1]-mx), e2 = exp(lg[2]-mx);
    double es = e0+e1+e2;
    double w[3] = { e0/es, e1/es, e2/es };

    // f64 inverse norms of the query, per modality
    double invu[3];
#pragma unroll
    for (int m=0;m<3;m++){
        float4 a = *(const float4*)&unl[ (((size_t)u*M_CNT)+m)*D_CNT + lane*4 ];
        double sS = (double)a.x*a.x + (double)a.y*a.y + (double)a.z*a.z + (double)a.w*a.w;
#pragma unroll
        for (int mm=1;mm<64;mm<<=1) sS += dshfl_xor(sS, mm);
        invu[m] = 1.0/(sqrt(sS) + 1e-8);
    }

    double cv[KC]; int ci[KC];
#pragma unroll
    for (int c=0;c<KC;c++){
        int idx = candIdx[ (((size_t)u*T_CNT)+t)*KC + c ];
        double sim = 0.0;
#pragma unroll
        for (int m=0;m<3;m++){
            float4 a = *(const float4*)&unl[ (((size_t)u*M_CNT)+m)*D_CNT + lane*4 ];
            float4 b = *(const float4*)&lab[ (((size_t)idx*M_CNT)+m)*D_CNT + lane*4 ];
            double d  = (double)a.x*b.x + (double)a.y*b.y + (double)a.z*b.z + (double)a.w*b.w;
            double nb = (double)b.x*b.x + (double)b.y*b.y + (double)b.z*b.z + (double)b.w*b.w;
#pragma unroll
            for (int mm=1;mm<64;mm<<=1){ d += dshfl_xor(d, mm); nb += dshfl_xor(nb, mm); }
            sim += w[m] * (d * invu[m] * (1.0/(sqrt(nb) + 1e-8)));
        }
        cv[c] = sim; ci[c] = idx;
    }
    // full bubble sort desc, tie -> smaller index first (matches lax.top_k stability)
#pragma unroll
    for (int i=0;i<KC;i++)
#pragma unroll
        for (int j=0;j<KC-1;j++){
            bool sw = (cv[j] < cv[j+1]) || (cv[j] == cv[j+1] && ci[j] > ci[j+1]);
            if (sw){ double tv=cv[j]; cv[j]=cv[j+1]; cv[j+1]=tv; int ti=ci[j]; ci[j]=ci[j+1]; ci[j+1]=ti; }
        }
    if (lane == 0){
#pragma unroll
        for (int k=0;k<K_OUT;k++){
            size_t ob = (((size_t)u*T_CNT)+t)*K_OUT + k;
            int fi = ci[k];
            outTraits[ob] = traits[(size_t)fi*T_CNT + t];
            outIdx[ob] = (float)fi;
            finalIdx[ob] = fi;
        }
    }
}

// -------- K5: embedding gather --------
// grid: U*T*K blocks; block 192 (= 768 floats / 4 per thread).
__global__ __launch_bounds__(192) void gather_kernel(const float* __restrict__ lab,
    const int* __restrict__ finalIdx, float* __restrict__ outEmb)
{
    int b = blockIdx.x;
    int idx = finalIdx[b];
    const float4* src = (const float4*)(lab + (size_t)idx * (M_CNT*D_CNT));
    float4* dst = (float4*)(outEmb + (size_t)b * (M_CNT*D_CNT));
    dst[threadIdx.x] = src[threadIdx.x];
}

extern "C" void kernel_launch(void* const* d_in, const int* in_sizes, int n_in,
                              void* d_out, int out_size, void* d_ws, size_t ws_size,
                              hipStream_t stream) {
    const float* lab    = (const float*)d_in[0];   // [20000,3,256]
    const float* traits = (const float*)d_in[1];   // [20000,5]
    const float* unl    = (const float*)d_in[2];   // [2048,3,256]
    const float* logits = (const float*)d_in[3];   // [5,3]

    float* out = (float*)d_out;
    float* outEmb = out;                                           // 62,914,560
    float* outTr  = out + (size_t)U_CNT*T_CNT*K_OUT*M_CNT*D_CNT;   // +81,920
    float* outIx  = outTr + (size_t)U_CNT*T_CNT*K_OUT;             // +81,920

    // workspace carve (256B aligned)
    char* wsb = (char*)d_ws;
    size_t off = 0;
    auto take = [&](size_t bytes)->void*{
        void* p = wsb + off;
        off = (off + bytes + 255) & ~(size_t)255;
        return p;
    };
    float* labInv  = (float*)take((size_t)L_CNT*M_CNT*sizeof(float));
    float* unlInv  = (float*)take((size_t)U_CNT*M_CNT*sizeof(float));
    float* w32     = (float*)take(T_CNT*M_CNT*sizeof(float));
    float* candVal = (float*)take((size_t)U_CNT*T_CNT*KC*sizeof(float));
    int*   candIdx = (int*)  take((size_t)U_CNT*T_CNT*KC*sizeof(int));
    int*   finalIdx= (int*)  take((size_t)U_CNT*T_CNT*K_OUT*sizeof(int));
    float* slabBuf = (float*)take((size_t)SLAB*T_CNT*L_CNT*sizeof(float));  // 51.2 MB

    weights_kernel<<<1, 64, 0, stream>>>(logits, w32);
    {
        int nrow = L_CNT*M_CNT + U_CNT*M_CNT;           // 66144
        norm_kernel<<<(nrow+3)/4, 256, 0, stream>>>(lab, unl, labInv, unlInv);
    }
    const int LTILES = (L_CNT + TL - 1)/TL;             // 157
    for (int s = 0; s < NSLAB; ++s){
        sim_kernel<<<dim3(LTILES, SLAB/TU), 256, 0, stream>>>(lab, unl, labInv, unlInv, w32, slabBuf, s);
        select_kernel<<<dim3(SLAB, T_CNT), 256, 0, stream>>>(slabBuf, candVal, candIdx, s);
    }
    rescore_kernel<<<dim3(U_CNT, T_CNT), 64, 0, stream>>>(lab, unl, traits, logits, candIdx, outTr, outIx, finalIdx);
    gather_kernel<<<U_CNT*T_CNT*K_OUT, 192, 0, stream>>>(lab, finalIdx, outEmb);
}

// Round 2
// 2789.917 us; speedup vs baseline: 1.8847x; 1.8847x over previous
//
#include <hip/hip_runtime.h>
#include <hip/hip_bf16.h>
#include <math.h>

#define L_CNT 20000
#define U_CNT 2048
#define M_CNT 3
#define D_CNT 256
#define T_CNT 5
#define K_OUT 8
#define KC    16
#define SLAB  128
#define NSLAB (U_CNT/SLAB)
#define LP    20032              // padded row stride for sim slab (fp16)
#define LROWS (L_CNT*M_CNT)      // 60000
#define UROWS (U_CNT*M_CNT)      // 6144

typedef __attribute__((ext_vector_type(8))) short bf16x8;
typedef __attribute__((ext_vector_type(4))) float f32x4;

// -------- helpers --------
__device__ inline double dshfl_xor(double v, int m){
    long long x = __double_as_longlong(v);
    int lo = (int)(x & 0xffffffffLL);
    int hi = (int)(((unsigned long long)x) >> 32);
    lo = __shfl_xor(lo, m, 64);
    hi = __shfl_xor(hi, m, 64);
    return __longlong_as_double(((long long)hi << 32) | (long long)(unsigned int)lo);
}
__device__ inline unsigned short f2bf(float f){
    unsigned int u = __float_as_uint(f);
    u = (u + 0x7fffu + ((u >> 16) & 1u)) >> 16;
    return (unsigned short)u;
}

// -------- K0: softmax weights (f32 for GEMM epilogue, f64 for rescore) --------
__global__ void weights_kernel(const float* __restrict__ logits,
                               float* __restrict__ w32, double* __restrict__ w64){
    int t = threadIdx.x;
    if (t < T_CNT){
        float a = logits[t*M_CNT+0], b = logits[t*M_CNT+1], c = logits[t*M_CNT+2];
        float mx = fmaxf(a, fmaxf(b, c));
        float e0 = expf(a-mx), e1 = expf(b-mx), e2 = expf(c-mx);
        float s = e0+e1+e2;
        w32[t*M_CNT+0] = e0/s; w32[t*M_CNT+1] = e1/s; w32[t*M_CNT+2] = e2/s;
        double da=(double)a, db=(double)b, dc=(double)c;
        double dmx = fmax(da, fmax(db, dc));
        double f0 = exp(da-dmx), f1 = exp(db-dmx), f2 = exp(dc-dmx);
        double ds = f0+f1+f2;
        w64[t*M_CNT+0] = f0/ds; w64[t*M_CNT+1] = f1/ds; w64[t*M_CNT+2] = f2/ds;
    }
}

// -------- K1: inverse norms (f64 + f32 copies) --------
__global__ __launch_bounds__(256) void prep_kernel(const float* __restrict__ lab,
    const float* __restrict__ unl, double* __restrict__ invL64, double* __restrict__ invU64,
    float* __restrict__ invL32, float* __restrict__ invU32){
    const int NROW = LROWS + UROWS;
    int row = blockIdx.x*4 + (threadIdx.x >> 6);
    int lane = threadIdx.x & 63;
    if (row >= NROW) return;
    bool isLab = row < LROWS;
    const float* p = isLab ? (lab + (size_t)row*D_CNT) : (unl + (size_t)(row-LROWS)*D_CNT);
    float4 a = ((const float4*)p)[lane];
    double s = (double)a.x*a.x + (double)a.y*a.y + (double)a.z*a.z + (double)a.w*a.w;
#pragma unroll
    for (int m=1;m<64;m<<=1) s += dshfl_xor(s, m);
    if (lane == 0){
        double inv = 1.0/(sqrt(s) + 1e-8);
        if (isLab){ invL64[row] = inv; invL32[row] = (float)inv; }
        else { invU64[row-LROWS] = inv; invU32[row-LROWS] = (float)inv; }
    }
}

// -------- K2: MFMA bf16 sim GEMM, combined-trait fp16 output --------
// grid (313, 2) per slab; block 256 (4 waves, 2x2). Block tile 64u x 64l.
__global__ __launch_bounds__(256) void sim_kernel(const float* __restrict__ lab,
    const float* __restrict__ unl, const float* __restrict__ invL32,
    const float* __restrict__ invU32, const float* __restrict__ w32,
    _Float16* __restrict__ slabp, int s)
{
    __shared__ unsigned short sA[64][72];
    __shared__ unsigned short sB[64][72];
    __shared__ float sT[64][68];

    const int tid  = threadIdx.x;
    const int lane = tid & 63;
    const int wave = tid >> 6;
    const int wu = wave >> 1;              // 0..1
    const int wl = wave & 1;               // 0..1
    const int fr = lane & 15;
    const int fg = lane >> 4;

    const int l0  = blockIdx.x * 64;
    const int uB  = blockIdx.y * 64;       // within slab
    const int gu0 = s*SLAB + uB;

    // staging role
    const int arow = tid >> 2;             // 0..63
    const int ac0  = (tid & 3) * 16;       // 0,16,32,48
    const int lrow = l0 + arow;
    const bool lOk = (lrow < L_CNT);

    float w[T_CNT][M_CNT];
#pragma unroll
    for (int t=0;t<T_CNT;t++)
#pragma unroll
        for (int m=0;m<M_CNT;m++) w[t][m] = w32[t*M_CNT+m];

    f32x4 comb[T_CNT][2][2];
#pragma unroll
    for (int t=0;t<T_CNT;t++)
#pragma unroll
        for (int i=0;i<2;i++)
#pragma unroll
            for (int j=0;j<2;j++) comb[t][i][j] = (f32x4){0.f,0.f,0.f,0.f};

    for (int m=0;m<M_CNT;m++){
        const float scA = invU32[(gu0+arow)*M_CNT + m];
        const float scB = lOk ? invL32[lrow*M_CNT + m] : 0.f;
        const float* srcA = &unl[(((size_t)(gu0+arow))*M_CNT + m)*D_CNT];
        const float* srcB = lOk ? &lab[(((size_t)lrow)*M_CNT + m)*D_CNT] : nullptr;

        f32x4 acc[2][2];
#pragma unroll
        for (int i=0;i<2;i++)
#pragma unroll
            for (int j=0;j<2;j++) acc[i][j] = (f32x4){0.f,0.f,0.f,0.f};

        for (int kb=0;kb<D_CNT;kb+=64){
            __syncthreads();
            // stage A (unl, normalized bf16)
            {
                float4 v0 = *(const float4*)&srcA[kb+ac0+0];
                float4 v1 = *(const float4*)&srcA[kb+ac0+4];
                float4 v2 = *(const float4*)&srcA[kb+ac0+8];
                float4 v3 = *(const float4*)&srcA[kb+ac0+12];
                bf16x8 r0, r1;
                r0[0]=f2bf(v0.x*scA); r0[1]=f2bf(v0.y*scA); r0[2]=f2bf(v0.z*scA); r0[3]=f2bf(v0.w*scA);
                r0[4]=f2bf(v1.x*scA); r0[5]=f2bf(v1.y*scA); r0[6]=f2bf(v1.z*scA); r0[7]=f2bf(v1.w*scA);
                r1[0]=f2bf(v2.x*scA); r1[1]=f2bf(v2.y*scA); r1[2]=f2bf(v2.z*scA); r1[3]=f2bf(v2.w*scA);
                r1[4]=f2bf(v3.x*scA); r1[5]=f2bf(v3.y*scA); r1[6]=f2bf(v3.z*scA); r1[7]=f2bf(v3.w*scA);
                *(bf16x8*)&sA[arow][ac0]   = r0;
                *(bf16x8*)&sA[arow][ac0+8] = r1;
            }
            // stage B (lab, normalized bf16; zero-fill OOB rows)
            {
                float4 v0=make_float4(0,0,0,0), v1=v0, v2=v0, v3=v0;
                if (lOk){
                    v0 = *(const float4*)&srcB[kb+ac0+0];
                    v1 = *(const float4*)&srcB[kb+ac0+4];
                    v2 = *(const float4*)&srcB[kb+ac0+8];
                    v3 = *(const float4*)&srcB[kb+ac0+12];
                }
                bf16x8 r0, r1;
                r0[0]=f2bf(v0.x*scB); r0[1]=f2bf(v0.y*scB); r0[2]=f2bf(v0.z*scB); r0[3]=f2bf(v0.w*scB);
                r0[4]=f2bf(v1.x*scB); r0[5]=f2bf(v1.y*scB); r0[6]=f2bf(v1.z*scB); r0[7]=f2bf(v1.w*scB);
                r1[0]=f2bf(v2.x*scB); r1[1]=f2bf(v2.y*scB); r1[2]=f2bf(v2.z*scB); r1[3]=f2bf(v2.w*scB);
                r1[4]=f2bf(v3.x*scB); r1[5]=f2bf(v3.y*scB); r1[6]=f2bf(v3.z*scB); r1[7]=f2bf(v3.w*scB);
                *(bf16x8*)&sB[arow][ac0]   = r0;
                *(bf16x8*)&sB[arow][ac0+8] = r1;
            }
            __syncthreads();
#pragma unroll
            for (int ks=0;ks<2;ks++){
                bf16x8 af[2], bfv[2];
#pragma unroll
                for (int i=0;i<2;i++) af[i]  = *(const bf16x8*)&sA[wu*32+i*16+fr][ks*32+fg*8];
#pragma unroll
                for (int j=0;j<2;j++) bfv[j] = *(const bf16x8*)&sB[wl*32+j*16+fr][ks*32+fg*8];
#pragma unroll
                for (int i=0;i<2;i++)
#pragma unroll
                    for (int j=0;j<2;j++)
                        acc[i][j] = __builtin_amdgcn_mfma_f32_16x16x32_bf16(af[i], bfv[j], acc[i][j], 0, 0, 0);
            }
        }
        // fold modality into per-trait combination
#pragma unroll
        for (int t=0;t<T_CNT;t++){
            float wm = w[t][m];
#pragma unroll
            for (int i=0;i<2;i++)
#pragma unroll
                for (int j=0;j<2;j++){
                    comb[t][i][j][0] += wm*acc[i][j][0];
                    comb[t][i][j][1] += wm*acc[i][j][1];
                    comb[t][i][j][2] += wm*acc[i][j][2];
                    comb[t][i][j][3] += wm*acc[i][j][3];
                }
        }
    }

    // epilogue: LDS transpose per trait, coalesced fp16 stores
    for (int t=0;t<T_CNT;t++){
        __syncthreads();
#pragma unroll
        for (int i=0;i<2;i++)
#pragma unroll
            for (int j=0;j<2;j++)
#pragma unroll
                for (int r=0;r<4;r++)
                    sT[wu*32+i*16+fg*4+r][wl*32+j*16+fr] = comb[t][i][j][r];
        __syncthreads();
        {
            int row = tid >> 2;
            int c0  = (tid & 3) * 16;
            _Float16 h[16];
#pragma unroll
            for (int e=0;e<16;e++) h[e] = (_Float16)sT[row][c0+e];
            size_t base = (((size_t)(uB+row))*T_CNT + t)*LP + l0 + c0;
            *(uint4*)&slabp[base]   = *(const uint4*)&h[0];
            *(uint4*)&slabp[base+8] = *(const uint4*)&h[8];
        }
    }
}

// -------- K3: exact top-KC per (u,t) from fp16 slab --------
__global__ __launch_bounds__(256) void select_kernel(const _Float16* __restrict__ slabp,
    int* __restrict__ candIdx, int s)
{
    const int ul = blockIdx.x;
    const int t  = blockIdx.y;
    const int gu = s*SLAB + ul;
    const _Float16* row = slabp + ((size_t)ul*T_CNT + t)*LP;
    const int tid = threadIdx.x;

    float bv[KC]; int bi[KC];
#pragma unroll
    for (int i=0;i<KC;i++){ bv[i] = -INFINITY; bi[i] = 0x7fffffff; }

    for (int l8 = tid; l8 < L_CNT/8; l8 += 256){
        uint4 pk = *(const uint4*)&row[l8*8];
        const _Float16* hv = (const _Float16*)&pk;
#pragma unroll
        for (int e=0;e<8;e++){
            float v = (float)hv[e];
            int l = l8*8 + e;
            if (v > bv[KC-1] || (v == bv[KC-1] && l < bi[KC-1])){
                int rank = 0;
#pragma unroll
                for (int p=0;p<KC;p++) rank += ((bv[p] > v) || (bv[p] == v && bi[p] < l)) ? 1 : 0;
#pragma unroll
                for (int p=KC-1;p>0;--p){ if (p > rank){ bv[p]=bv[p-1]; bi[p]=bi[p-1]; } }
#pragma unroll
                for (int p=0;p<KC;p++){ if (p == rank){ bv[p]=v; bi[p]=l; } }
            }
        }
    }

    __shared__ float wvs[4]; __shared__ int wis[4]; __shared__ int wts[4];
    __shared__ int sbt;
    const int lane = tid & 63, wid = tid >> 6;

    for (int k=0;k<KC;k++){
        float cv = bv[0]; int ci = bi[0]; int ct = tid;
#pragma unroll
        for (int mm=1;mm<64;mm<<=1){
            float ov = __shfl_xor(cv, mm, 64);
            int oi = __shfl_xor(ci, mm, 64);
            int ot = __shfl_xor(ct, mm, 64);
            if (ov > cv || (ov == cv && (oi < ci || (oi == ci && ot < ct)))){ cv=ov; ci=oi; ct=ot; }
        }
        if (lane == 0){ wvs[wid]=cv; wis[wid]=ci; wts[wid]=ct; }
        __syncthreads();
        if (tid == 0){
            float fv = wvs[0]; int fi = wis[0]; int ft = wts[0];
#pragma unroll
            for (int q=1;q<4;q++){
                float ov=wvs[q]; int oi=wis[q]; int ot=wts[q];
                if (ov > fv || (ov == fv && (oi < fi || (oi == fi && ot < ft)))){ fv=ov; fi=oi; ft=ot; }
            }
            candIdx[((size_t)gu*T_CNT + t)*KC + k] = fi;
            sbt = ft;
        }
        __syncthreads();
        if (tid == sbt){
#pragma unroll
            for (int p=0;p<KC-1;p++){ bv[p]=bv[p+1]; bi[p]=bi[p+1]; }
            bv[KC-1] = -INFINITY; bi[KC-1] = 0x7fffffff;
        }
        __syncthreads();
    }
}

// -------- K4: f64 rescore, one wave per (u,t,candidate) --------
__global__ __launch_bounds__(256) void rescore_kernel(
    const float* __restrict__ lab, const float* __restrict__ unl,
    const double* __restrict__ w64, const double* __restrict__ invL64,
    const double* __restrict__ invU64, const int* __restrict__ candIdx,
    double* __restrict__ candSim)
{
    int q = blockIdx.x*4 + (threadIdx.x >> 6);      // 0 .. U*T*KC-1
    int lane = threadIdx.x & 63;
    int ut = q >> 4;                                 // u*T + t
    int t = ut % T_CNT;
    int u = ut / T_CNT;
    int idx = candIdx[q];
    double sim = 0.0;
#pragma unroll
    for (int m=0;m<M_CNT;m++){
        float4 a = *(const float4*)&unl[(((size_t)u*M_CNT)+m)*D_CNT + lane*4];
        float4 b = *(const float4*)&lab[(((size_t)idx*M_CNT)+m)*D_CNT + lane*4];
        double d = (double)a.x*b.x + (double)a.y*b.y + (double)a.z*b.z + (double)a.w*b.w;
#pragma unroll
        for (int mm=1;mm<64;mm<<=1) d += dshfl_xor(d, mm);
        sim += w64[t*M_CNT+m] * d * invU64[u*M_CNT+m] * invL64[idx*M_CNT+m];
    }
    if (lane == 0) candSim[q] = sim;
}

// -------- K5: sort 16 candidates per (u,t), emit traits/index outputs --------
__global__ __launch_bounds__(256) void finalize_kernel(
    const double* __restrict__ candSim, const int* __restrict__ candIdx,
    const float* __restrict__ traits,
    float* __restrict__ outTraits, float* __restrict__ outIdx, int* __restrict__ finalIdx)
{
    int id = blockIdx.x*256 + threadIdx.x;
    if (id >= U_CNT*T_CNT) return;
    int t = id % T_CNT;
    double cv[KC]; int ci[KC];
#pragma unroll
    for (int c=0;c<KC;c++){ cv[c] = candSim[(size_t)id*KC + c]; ci[c] = candIdx[(size_t)id*KC + c]; }
#pragma unroll
    for (int i=0;i<KC;i++)
#pragma unroll
        for (int j=0;j<KC-1;j++){
            bool sw = (cv[j] < cv[j+1]) || (cv[j] == cv[j+1] && ci[j] > ci[j+1]);
            if (sw){ double tv=cv[j]; cv[j]=cv[j+1]; cv[j+1]=tv; int ti=ci[j]; ci[j]=ci[j+1]; ci[j+1]=ti; }
        }
#pragma unroll
    for (int k=0;k<K_OUT;k++){
        size_t ob = (size_t)id*K_OUT + k;
        int fi = ci[k];
        outTraits[ob] = traits[(size_t)fi*T_CNT + t];
        outIdx[ob] = (float)fi;
        finalIdx[ob] = fi;
    }
}

// -------- K6: embedding gather --------
__global__ __launch_bounds__(192) void gather_kernel(const float* __restrict__ lab,
    const int* __restrict__ finalIdx, float* __restrict__ outEmb)
{
    int b = blockIdx.x;
    int idx = finalIdx[b];
    const float4* src = (const float4*)(lab + (size_t)idx * (M_CNT*D_CNT));
    float4* dst = (float4*)(outEmb + (size_t)b * (M_CNT*D_CNT));
    dst[threadIdx.x] = src[threadIdx.x];
}

extern "C" void kernel_launch(void* const* d_in, const int* in_sizes, int n_in,
                              void* d_out, int out_size, void* d_ws, size_t ws_size,
                              hipStream_t stream) {
    const float* lab    = (const float*)d_in[0];   // [20000,3,256]
    const float* traits = (const float*)d_in[1];   // [20000,5]
    const float* unl    = (const float*)d_in[2];   // [2048,3,256]
    const float* logits = (const float*)d_in[3];   // [5,3]

    float* out = (float*)d_out;
    float* outEmb = out;                                           // U*T*K*M*D
    float* outTr  = out + (size_t)U_CNT*T_CNT*K_OUT*M_CNT*D_CNT;
    float* outIx  = outTr + (size_t)U_CNT*T_CNT*K_OUT;

    char* wsb = (char*)d_ws;
    size_t off = 0;
    auto take = [&](size_t bytes)->void*{
        void* p = wsb + off;
        off = (off + bytes + 255) & ~(size_t)255;
        return p;
    };
    double* invL64 = (double*)take((size_t)LROWS*sizeof(double));
    double* invU64 = (double*)take((size_t)UROWS*sizeof(double));
    float*  invL32 = (float*) take((size_t)LROWS*sizeof(float));
    float*  invU32 = (float*) take((size_t)UROWS*sizeof(float));
    float*  w32    = (float*) take(T_CNT*M_CNT*sizeof(float));
    double* w64    = (double*)take(T_CNT*M_CNT*sizeof(double));
    int*    candIdx= (int*)   take((size_t)U_CNT*T_CNT*KC*sizeof(int));
    double* candSim= (double*)take((size_t)U_CNT*T_CNT*KC*sizeof(double));
    int*    finalIdx=(int*)   take((size_t)U_CNT*T_CNT*K_OUT*sizeof(int));
    _Float16* slabF16 = (_Float16*)take((size_t)SLAB*T_CNT*LP*sizeof(_Float16)); // 25.6 MB

    weights_kernel<<<1, 64, 0, stream>>>(logits, w32, w64);
    {
        int nrow = LROWS + UROWS;
        prep_kernel<<<(nrow+3)/4, 256, 0, stream>>>(lab, unl, invL64, invU64, invL32, invU32);
    }
    const int LTILES = (L_CNT + 63)/64;              // 313
    for (int s = 0; s < NSLAB; ++s){
        sim_kernel<<<dim3(LTILES, SLAB/64), 256, 0, stream>>>(lab, unl, invL32, invU32, w32, slabF16, s);
        select_kernel<<<dim3(SLAB, T_CNT), 256, 0, stream>>>(slabF16, candIdx, s);
    }
    rescore_kernel<<<(U_CNT*T_CNT*KC)/4, 256, 0, stream>>>(lab, unl, w64, invL64, invU64, candIdx, candSim);
    finalize_kernel<<<(U_CNT*T_CNT + 255)/256, 256, 0, stream>>>(candSim, candIdx, traits, outTr, outIx, finalIdx);
    gather_kernel<<<U_CNT*T_CNT*K_OUT, 192, 0, stream>>>(lab, finalIdx, outEmb);
}

// Round 3
// 1407.106 us; speedup vs baseline: 3.7370x; 1.9827x over previous
//
#include <hip/hip_runtime.h>
#include <hip/hip_bf16.h>
#include <math.h>

#define L_CNT 20000
#define U_CNT 2048
#define M_CNT 3
#define D_CNT 256
#define KTOT  768
#define T_CNT 5
#define K_OUT 8
#define KC    16
#define SLAB  1024
#define NSLAB (U_CNT/SLAB)
#define LP    20032              // 313*64, padded fp16 row stride
#define LROWS (L_CNT*M_CNT)      // 60000
#define UROWS (U_CNT*M_CNT)      // 6144

typedef unsigned short ushort_t;
typedef __attribute__((ext_vector_type(8))) short bf16x8;
typedef __attribute__((ext_vector_type(4))) float f32x4;

// -------- helpers --------
__device__ inline double dshfl_xor(double v, int m){
    long long x = __double_as_longlong(v);
    int lo = (int)(x & 0xffffffffLL);
    int hi = (int)(((unsigned long long)x) >> 32);
    lo = __shfl_xor(lo, m, 64);
    hi = __shfl_xor(hi, m, 64);
    return __longlong_as_double(((long long)hi << 32) | (long long)(unsigned int)lo);
}
__device__ inline unsigned short f2bf(float f){
    unsigned int u = __float_as_uint(f);
    u = (u + 0x7fffu + ((u >> 16) & 1u)) >> 16;
    return (unsigned short)u;
}
__device__ __forceinline__ void gload16(const void* g, void* l){
    __builtin_amdgcn_global_load_lds(
        (const __attribute__((address_space(1))) unsigned int*)g,
        (__attribute__((address_space(3))) unsigned int*)l, 16, 0, 0);
}

// -------- K0: softmax weights --------
__global__ void weights_kernel(const float* __restrict__ logits,
                               float* __restrict__ w32, double* __restrict__ w64){
    int t = threadIdx.x;
    if (t < T_CNT){
        float a = logits[t*M_CNT+0], b = logits[t*M_CNT+1], c = logits[t*M_CNT+2];
        float mx = fmaxf(a, fmaxf(b, c));
        float e0 = expf(a-mx), e1 = expf(b-mx), e2 = expf(c-mx);
        float s = e0+e1+e2;
        w32[t*M_CNT+0] = e0/s; w32[t*M_CNT+1] = e1/s; w32[t*M_CNT+2] = e2/s;
        double da=(double)a, db=(double)b, dc=(double)c;
        double dmx = fmax(da, fmax(db, dc));
        double f0 = exp(da-dmx), f1 = exp(db-dmx), f2 = exp(dc-dmx);
        double ds = f0+f1+f2;
        w64[t*M_CNT+0] = f0/ds; w64[t*M_CNT+1] = f1/ds; w64[t*M_CNT+2] = f2/ds;
    }
}

// -------- K1: f64 inv-norms + normalized bf16 copies (once) --------
__global__ __launch_bounds__(256) void prep_kernel(const float* __restrict__ lab,
    const float* __restrict__ unl, double* __restrict__ invL64, double* __restrict__ invU64,
    ushort_t* __restrict__ labN, ushort_t* __restrict__ unlN){
    const int NROW = LROWS + UROWS;
    int row = blockIdx.x*4 + (threadIdx.x >> 6);
    int lane = threadIdx.x & 63;
    if (row >= NROW) return;
    bool isLab = row < LROWS;
    const float* p = isLab ? (lab + (size_t)row*D_CNT) : (unl + (size_t)(row-LROWS)*D_CNT);
    float4 a = ((const float4*)p)[lane];
    double sS = (double)a.x*a.x + (double)a.y*a.y + (double)a.z*a.z + (double)a.w*a.w;
#pragma unroll
    for (int m=1;m<64;m<<=1) sS += dshfl_xor(sS, m);
    double inv = 1.0/(sqrt(sS) + 1e-8);
    if (lane == 0){
        if (isLab) invL64[row] = inv;
        else invU64[row-LROWS] = inv;
    }
    float sc = (float)inv;
    ushort4 o;
    o.x = f2bf(a.x*sc); o.y = f2bf(a.y*sc); o.z = f2bf(a.z*sc); o.w = f2bf(a.w*sc);
    ushort_t* dst = isLab ? (labN + (size_t)row*D_CNT) : (unlN + (size_t)(row-LROWS)*D_CNT);
    *(ushort4*)&dst[lane*4] = o;
}

// -------- K2: bf16 MFMA sim GEMM (global_load_lds + XOR-swizzled LDS) --------
// grid (SLAB/64, 313); block 256 (4 waves 2x2). K=768 contiguous (3 modalities folded).
__global__ __launch_bounds__(256) void sim_kernel(
    const ushort_t* __restrict__ labN, const ushort_t* __restrict__ unlN,
    const float* __restrict__ w32, _Float16* __restrict__ slabp, int s)
{
    __shared__ ushort_t sA[64][64];
    __shared__ ushort_t sB[64][64];
    __shared__ float sT[64][68];

    const int tid  = threadIdx.x;
    const int lane = tid & 63;
    const int w    = tid >> 6;
    const int wu = w >> 1, wl = w & 1;
    const int fr = lane & 15, fg = lane >> 4;

    const int uB  = blockIdx.x * 64;         // within slab
    const int gu0 = s*SLAB + uB;
    const int l0  = blockIdx.y * 64;

    // ---- staging setup (pre-swizzled global source, linear LDS dest) ----
    const int sr   = lane >> 3;                  // 0..7 sub-row
    const int scol = ((lane & 7) ^ sr) * 8;      // swizzled source col (elements)
    const ushort_t* pA0 = unlN + (size_t)(gu0 + w*8 + sr)*KTOT + scol;
    const ushort_t* pA1 = pA0 + (size_t)32*KTOT;
    int lr0 = l0 + w*8 + sr;      if (lr0 > L_CNT-1) lr0 = L_CNT-1;
    int lr1 = l0 + w*8 + 32 + sr; if (lr1 > L_CNT-1) lr1 = L_CNT-1;
    const ushort_t* pB0 = labN + (size_t)lr0*KTOT + scol;
    const ushort_t* pB1 = labN + (size_t)lr1*KTOT + scol;
    ushort_t* dA0 = &sA[w*8][0];
    ushort_t* dA1 = &sA[w*8+32][0];
    ushort_t* dB0 = &sB[w*8][0];
    ushort_t* dB1 = &sB[w*8+32][0];

    // ---- fragment read byte-offsets (with matching XOR swizzle) ----
    int aoff[2][2], boff[2][2];
#pragma unroll
    for (int i=0;i<2;i++)
#pragma unroll
        for (int ks=0;ks<2;ks++){
            int sw = (((ks<<2)|fg) ^ (fr & 7)) << 4;
            aoff[i][ks] = (wu*32 + i*16 + fr)*128 + sw;
            boff[i][ks] = (wl*32 + i*16 + fr)*128 + sw;
        }

    float wloc[T_CNT][M_CNT];
#pragma unroll
    for (int t=0;t<T_CNT;t++)
#pragma unroll
        for (int m=0;m<M_CNT;m++) wloc[t][m] = w32[t*M_CNT+m];

    f32x4 comb[T_CNT][2][2];
#pragma unroll
    for (int t=0;t<T_CNT;t++)
#pragma unroll
        for (int i=0;i<2;i++)
#pragma unroll
            for (int j=0;j<2;j++) comb[t][i][j] = (f32x4){0.f,0.f,0.f,0.f};

#pragma unroll
    for (int m=0;m<M_CNT;m++){
        f32x4 acc[2][2];
#pragma unroll
        for (int i=0;i<2;i++)
#pragma unroll
            for (int j=0;j<2;j++) acc[i][j] = (f32x4){0.f,0.f,0.f,0.f};
#pragma unroll
        for (int kb=0;kb<4;kb++){
            const int koff = (m*4 + kb) * 64;   // elements
            __syncthreads();
            gload16(pA0 + koff, dA0);
            gload16(pA1 + koff, dA1);
            gload16(pB0 + koff, dB0);
            gload16(pB1 + koff, dB1);
            __syncthreads();
#pragma unroll
            for (int ks=0;ks<2;ks++){
                bf16x8 af0 = *(const bf16x8*)((const char*)sA + aoff[0][ks]);
                bf16x8 af1 = *(const bf16x8*)((const char*)sA + aoff[1][ks]);
                bf16x8 bf0 = *(const bf16x8*)((const char*)sB + boff[0][ks]);
                bf16x8 bf1 = *(const bf16x8*)((const char*)sB + boff[1][ks]);
                acc[0][0] = __builtin_amdgcn_mfma_f32_16x16x32_bf16(af0, bf0, acc[0][0], 0, 0, 0);
                acc[0][1] = __builtin_amdgcn_mfma_f32_16x16x32_bf16(af0, bf1, acc[0][1], 0, 0, 0);
                acc[1][0] = __builtin_amdgcn_mfma_f32_16x16x32_bf16(af1, bf0, acc[1][0], 0, 0, 0);
                acc[1][1] = __builtin_amdgcn_mfma_f32_16x16x32_bf16(af1, bf1, acc[1][1], 0, 0, 0);
            }
        }
#pragma unroll
        for (int t=0;t<T_CNT;t++){
            float wm = wloc[t][m];
#pragma unroll
            for (int i=0;i<2;i++)
#pragma unroll
                for (int j=0;j<2;j++){
                    comb[t][i][j][0] += wm*acc[i][j][0];
                    comb[t][i][j][1] += wm*acc[i][j][1];
                    comb[t][i][j][2] += wm*acc[i][j][2];
                    comb[t][i][j][3] += wm*acc[i][j][3];
                }
        }
    }

    // ---- epilogue: LDS transpose per trait, coalesced fp16 stores ----
    for (int t=0;t<T_CNT;t++){
        __syncthreads();
#pragma unroll
        for (int i=0;i<2;i++)
#pragma unroll
            for (int j=0;j<2;j++)
#pragma unroll
                for (int r=0;r<4;r++)
                    sT[wu*32+i*16+fg*4+r][wl*32+j*16+fr] = comb[t][i][j][r];
        __syncthreads();
        {
            int row = tid >> 2;
            int c0  = (tid & 3) * 16;
            _Float16 h[16];
#pragma unroll
            for (int e=0;e<16;e++) h[e] = (_Float16)sT[row][c0+e];
            size_t base = (((size_t)(uB+row))*T_CNT + t)*LP + l0 + c0;
            *(uint4*)&slabp[base]   = *(const uint4*)&h[0];
            *(uint4*)&slabp[base+8] = *(const uint4*)&h[8];
        }
    }
}

// -------- K3: exact top-KC per (u,t) from fp16 slab --------
__global__ __launch_bounds__(256) void select_kernel(const _Float16* __restrict__ slabp,
    int* __restrict__ candIdx, int s)
{
    const int ul = blockIdx.x;
    const int t  = blockIdx.y;
    const int gu = s*SLAB + ul;
    const _Float16* row = slabp + ((size_t)ul*T_CNT + t)*LP;
    const int tid = threadIdx.x;

    float bv[KC]; int bi[KC];
#pragma unroll
    for (int i=0;i<KC;i++){ bv[i] = -INFINITY; bi[i] = 0x7fffffff; }

    for (int l8 = tid; l8 < L_CNT/8; l8 += 256){
        uint4 pk = *(const uint4*)&row[l8*8];
        const _Float16* hv = (const _Float16*)&pk;
#pragma unroll
        for (int e=0;e<8;e++){
            float v = (float)hv[e];
            int l = l8*8 + e;
            if (v > bv[KC-1] || (v == bv[KC-1] && l < bi[KC-1])){
                int rank = 0;
#pragma unroll
                for (int p=0;p<KC;p++) rank += ((bv[p] > v) || (bv[p] == v && bi[p] < l)) ? 1 : 0;
#pragma unroll
                for (int p=KC-1;p>0;--p){ if (p > rank){ bv[p]=bv[p-1]; bi[p]=bi[p-1]; } }
#pragma unroll
                for (int p=0;p<KC;p++){ if (p == rank){ bv[p]=v; bi[p]=l; } }
            }
        }
    }

    __shared__ float wvs[4]; __shared__ int wis[4]; __shared__ int wts[4];
    __shared__ int sbt;
    const int lane = tid & 63, wid = tid >> 6;

    for (int k=0;k<KC;k++){
        float cv = bv[0]; int ci = bi[0]; int ct = tid;
#pragma unroll
        for (int mm=1;mm<64;mm<<=1){
            float ov = __shfl_xor(cv, mm, 64);
            int oi = __shfl_xor(ci, mm, 64);
            int ot = __shfl_xor(ct, mm, 64);
            if (ov > cv || (ov == cv && (oi < ci || (oi == ci && ot < ct)))){ cv=ov; ci=oi; ct=ot; }
        }
        if (lane == 0){ wvs[wid]=cv; wis[wid]=ci; wts[wid]=ct; }
        __syncthreads();
        if (tid == 0){
            float fv = wvs[0]; int fi = wis[0]; int ft = wts[0];
#pragma unroll
            for (int q=1;q<4;q++){
                float ov=wvs[q]; int oi=wis[q]; int ot=wts[q];
                if (ov > fv || (ov == fv && (oi < fi || (oi == fi && ot < ft)))){ fv=ov; fi=oi; ft=ot; }
            }
            candIdx[((size_t)gu*T_CNT + t)*KC + k] = fi;
            sbt = ft;
        }
        __syncthreads();
        if (tid == sbt){
#pragma unroll
            for (int p=0;p<KC-1;p++){ bv[p]=bv[p+1]; bi[p]=bi[p+1]; }
            bv[KC-1] = -INFINITY; bi[KC-1] = 0x7fffffff;
        }
        __syncthreads();
    }
}

// -------- K4: f64 rescore, one wave per (u,t,candidate) --------
__global__ __launch_bounds__(256) void rescore_kernel(
    const float* __restrict__ lab, const float* __restrict__ unl,
    const double* __restrict__ w64, const double* __restrict__ invL64,
    const double* __restrict__ invU64, const int* __restrict__ candIdx,
    double* __restrict__ candSim)
{
    int q = blockIdx.x*4 + (threadIdx.x >> 6);      // 0 .. U*T*KC-1
    int lane = threadIdx.x & 63;
    int ut = q >> 4;                                 // u*T + t
    int t = ut % T_CNT;
    int u = ut / T_CNT;
    int idx = candIdx[q];
    double sim = 0.0;
#pragma unroll
    for (int m=0;m<M_CNT;m++){
        float4 a = *(const float4*)&unl[(((size_t)u*M_CNT)+m)*D_CNT + lane*4];
        float4 b = *(const float4*)&lab[(((size_t)idx*M_CNT)+m)*D_CNT + lane*4];
        double d = (double)a.x*b.x + (double)a.y*b.y + (double)a.z*b.z + (double)a.w*b.w;
#pragma unroll
        for (int mm=1;mm<64;mm<<=1) d += dshfl_xor(d, mm);
        sim += w64[t*M_CNT+m] * d * invU64[u*M_CNT+m] * invL64[idx*M_CNT+m];
    }
    if (lane == 0) candSim[q] = sim;
}

// -------- K5: sort 16 candidates per (u,t), emit traits/index outputs --------
__global__ __launch_bounds__(256) void finalize_kernel(
    const double* __restrict__ candSim, const int* __restrict__ candIdx,
    const float* __restrict__ traits,
    float* __restrict__ outTraits, float* __restrict__ outIdx, int* __restrict__ finalIdx)
{
    int id = blockIdx.x*256 + threadIdx.x;
    if (id >= U_CNT*T_CNT) return;
    int t = id % T_CNT;
    double cv[KC]; int ci[KC];
#pragma unroll
    for (int c=0;c<KC;c++){ cv[c] = candSim[(size_t)id*KC + c]; ci[c] = candIdx[(size_t)id*KC + c]; }
#pragma unroll
    for (int i=0;i<KC;i++)
#pragma unroll
        for (int j=0;j<KC-1;j++){
            bool sw = (cv[j] < cv[j+1]) || (cv[j] == cv[j+1] && ci[j] > ci[j+1]);
            if (sw){ double tv=cv[j]; cv[j]=cv[j+1]; cv[j+1]=tv; int ti=ci[j]; ci[j]=ci[j+1]; ci[j+1]=ti; }
        }
#pragma unroll
    for (int k=0;k<K_OUT;k++){
        size_t ob = (size_t)id*K_OUT + k;
        int fi = ci[k];
        outTraits[ob] = traits[(size_t)fi*T_CNT + t];
        outIdx[ob] = (float)fi;
        finalIdx[ob] = fi;
    }
}

// -------- K6: embedding gather --------
__global__ __launch_bounds__(192) void gather_kernel(const float* __restrict__ lab,
    const int* __restrict__ finalIdx, float* __restrict__ outEmb)
{
    int b = blockIdx.x;
    int idx = finalIdx[b];
    const float4* src = (const float4*)(lab + (size_t)idx * (M_CNT*D_CNT));
    float4* dst = (float4*)(outEmb + (size_t)b * (M_CNT*D_CNT));
    dst[threadIdx.x] = src[threadIdx.x];
}

extern "C" void kernel_launch(void* const* d_in, const int* in_sizes, int n_in,
                              void* d_out, int out_size, void* d_ws, size_t ws_size,
                              hipStream_t stream) {
    const float* lab    = (const float*)d_in[0];   // [20000,3,256]
    const float* traits = (const float*)d_in[1];   // [20000,5]
    const float* unl    = (const float*)d_in[2];   // [2048,3,256]
    const float* logits = (const float*)d_in[3];   // [5,3]

    float* out = (float*)d_out;
    float* outEmb = out;                                           // U*T*K*M*D = 62,914,560 f32
    float* outTr  = out + (size_t)U_CNT*T_CNT*K_OUT*M_CNT*D_CNT;
    float* outIx  = outTr + (size_t)U_CNT*T_CNT*K_OUT;

    char* wsb = (char*)d_ws;
    size_t off = 0;
    auto take = [&](size_t bytes)->void*{
        void* p = wsb + off;
        off = (off + bytes + 255) & ~(size_t)255;
        return p;
    };
    double* invL64 = (double*)take((size_t)LROWS*sizeof(double));
    double* invU64 = (double*)take((size_t)UROWS*sizeof(double));
    float*  w32    = (float*) take(T_CNT*M_CNT*sizeof(float));
    double* w64    = (double*)take(T_CNT*M_CNT*sizeof(double));
    int*    candIdx= (int*)   take((size_t)U_CNT*T_CNT*KC*sizeof(int));
    double* candSim= (double*)take((size_t)U_CNT*T_CNT*KC*sizeof(double));
    int*    finalIdx=(int*)   take((size_t)U_CNT*T_CNT*K_OUT*sizeof(int));
    ushort_t* labN = (ushort_t*)take((size_t)LROWS*D_CNT*sizeof(ushort_t)); // 30.7 MB
    ushort_t* unlN = (ushort_t*)take((size_t)UROWS*D_CNT*sizeof(ushort_t)); // 3.15 MB

    // sim slab lives in d_out's embedding region (written only by final gather):
    // SLAB*T_CNT*LP fp16 = 205.1 MB <= 251.6 MB region. Used and fully consumed
    // before gather_kernel runs.
    _Float16* slabF16 = (_Float16*)outEmb;

    weights_kernel<<<1, 64, 0, stream>>>(logits, w32, w64);
    {
        int nrow = LROWS + UROWS;
        prep_kernel<<<(nrow+3)/4, 256, 0, stream>>>(lab, unl, invL64, invU64, labN, unlN);
    }
    const int LTILES = (L_CNT + 63)/64;              // 313
    for (int s = 0; s < NSLAB; ++s){
        sim_kernel<<<dim3(SLAB/64, LTILES), 256, 0, stream>>>(labN, unlN, w32, slabF16, s);
        select_kernel<<<dim3(SLAB, T_CNT), 256, 0, stream>>>(slabF16, candIdx, s);
    }
    rescore_kernel<<<(U_CNT*T_CNT*KC)/4, 256, 0, stream>>>(lab, unl, w64, invL64, invU64, candIdx, candSim);
    finalize_kernel<<<(U_CNT*T_CNT + 255)/256, 256, 0, stream>>>(candSim, candIdx, traits, outTr, outIx, finalIdx);
    gather_kernel<<<U_CNT*T_CNT*K_OUT, 192, 0, stream>>>(lab, finalIdx, outEmb);
}

// Round 4
// 597.127 us; speedup vs baseline: 8.8060x; 2.3565x over previous
//
#include <hip/hip_runtime.h>
#include <hip/hip_bf16.h>
#include <math.h>

#define L_CNT 20000
#define U_CNT 2048
#define M_CNT 3
#define D_CNT 256
#define KTOT  768
#define T_CNT 5
#define K_OUT 8
#define KC    16
#define SLAB  1024
#define NSLAB (U_CNT/SLAB)
#define LP    20032              // 313*64, padded u16-key row stride
#define LROWS (L_CNT*M_CNT)      // 60000
#define UROWS (U_CNT*M_CNT)      // 6144

typedef unsigned short ushort_t;
typedef unsigned int uint_t;
typedef __attribute__((ext_vector_type(8))) short bf16x8;
typedef __attribute__((ext_vector_type(4))) float f32x4;

// -------- helpers --------
__device__ inline double dshfl_xor(double v, int m){
    long long x = __double_as_longlong(v);
    int lo = (int)(x & 0xffffffffLL);
    int hi = (int)(((unsigned long long)x) >> 32);
    lo = __shfl_xor(lo, m, 64);
    hi = __shfl_xor(hi, m, 64);
    return __longlong_as_double(((long long)hi << 32) | (long long)(unsigned int)lo);
}
__device__ inline unsigned short f2bf(float f){
    unsigned int u = __float_as_uint(f);
    u = (u + 0x7fffu + ((u >> 16) & 1u)) >> 16;
    return (unsigned short)u;
}
__device__ __forceinline__ void gload16(const void* g, void* l){
    __builtin_amdgcn_global_load_lds(
        (const __attribute__((address_space(1))) unsigned int*)g,
        (__attribute__((address_space(3))) unsigned int*)l, 16, 0, 0);
}
// fp16 bits -> sortable u16 key (unsigned compare == float compare)
__device__ __forceinline__ ushort_t h2key(ushort_t b){
    ushort_t mask = (ushort_t)(0x8000u | (((short)b >> 15) & 0x7FFF));
    return (ushort_t)(b ^ mask);
}

// -------- K0: softmax weights --------
__global__ void weights_kernel(const float* __restrict__ logits,
                               float* __restrict__ w32, double* __restrict__ w64){
    int t = threadIdx.x;
    if (t < T_CNT){
        float a = logits[t*M_CNT+0], b = logits[t*M_CNT+1], c = logits[t*M_CNT+2];
        float mx = fmaxf(a, fmaxf(b, c));
        float e0 = expf(a-mx), e1 = expf(b-mx), e2 = expf(c-mx);
        float s = e0+e1+e2;
        w32[t*M_CNT+0] = e0/s; w32[t*M_CNT+1] = e1/s; w32[t*M_CNT+2] = e2/s;
        double da=(double)a, db=(double)b, dc=(double)c;
        double dmx = fmax(da, fmax(db, dc));
        double f0 = exp(da-dmx), f1 = exp(db-dmx), f2 = exp(dc-dmx);
        double ds = f0+f1+f2;
        w64[t*M_CNT+0] = f0/ds; w64[t*M_CNT+1] = f1/ds; w64[t*M_CNT+2] = f2/ds;
    }
}

// -------- K1: f64 inv-norms + normalized bf16 copies (once) --------
__global__ __launch_bounds__(256) void prep_kernel(const float* __restrict__ lab,
    const float* __restrict__ unl, double* __restrict__ invL64, double* __restrict__ invU64,
    ushort_t* __restrict__ labN, ushort_t* __restrict__ unlN){
    const int NROW = LROWS + UROWS;
    int row = blockIdx.x*4 + (threadIdx.x >> 6);
    int lane = threadIdx.x & 63;
    if (row >= NROW) return;
    bool isLab = row < LROWS;
    const float* p = isLab ? (lab + (size_t)row*D_CNT) : (unl + (size_t)(row-LROWS)*D_CNT);
    float4 a = ((const float4*)p)[lane];
    double sS = (double)a.x*a.x + (double)a.y*a.y + (double)a.z*a.z + (double)a.w*a.w;
#pragma unroll
    for (int m=1;m<64;m<<=1) sS += dshfl_xor(sS, m);
    double inv = 1.0/(sqrt(sS) + 1e-8);
    if (lane == 0){
        if (isLab) invL64[row] = inv;
        else invU64[row-LROWS] = inv;
    }
    float sc = (float)inv;
    ushort4 o;
    o.x = f2bf(a.x*sc); o.y = f2bf(a.y*sc); o.z = f2bf(a.z*sc); o.w = f2bf(a.w*sc);
    ushort_t* dst = isLab ? (labN + (size_t)row*D_CNT) : (unlN + (size_t)(row-LROWS)*D_CNT);
    *(ushort4*)&dst[lane*4] = o;
}

// -------- K2: bf16 MFMA sim GEMM -> sortable u16 key slab --------
// grid (SLAB/64, 313); block 256 (4 waves 2x2). K=768 contiguous (3 modalities folded).
__global__ __launch_bounds__(256) void sim_kernel(
    const ushort_t* __restrict__ labN, const ushort_t* __restrict__ unlN,
    const float* __restrict__ w32, ushort_t* __restrict__ slabp, int s)
{
    __shared__ ushort_t sA[64][64];
    __shared__ ushort_t sB[64][64];
    __shared__ float sT[64][68];

    const int tid  = threadIdx.x;
    const int lane = tid & 63;
    const int w    = tid >> 6;
    const int wu = w >> 1, wl = w & 1;
    const int fr = lane & 15, fg = lane >> 4;

    const int uB  = blockIdx.x * 64;         // within slab
    const int gu0 = s*SLAB + uB;
    const int l0  = blockIdx.y * 64;

    // ---- staging setup (pre-swizzled global source, linear LDS dest) ----
    const int sr   = lane >> 3;                  // 0..7 sub-row
    const int scol = ((lane & 7) ^ sr) * 8;      // swizzled source col (elements)
    const ushort_t* pA0 = unlN + (size_t)(gu0 + w*8 + sr)*KTOT + scol;
    const ushort_t* pA1 = pA0 + (size_t)32*KTOT;
    int lr0 = l0 + w*8 + sr;      if (lr0 > L_CNT-1) lr0 = L_CNT-1;
    int lr1 = l0 + w*8 + 32 + sr; if (lr1 > L_CNT-1) lr1 = L_CNT-1;
    const ushort_t* pB0 = labN + (size_t)lr0*KTOT + scol;
    const ushort_t* pB1 = labN + (size_t)lr1*KTOT + scol;
    ushort_t* dA0 = &sA[w*8][0];
    ushort_t* dA1 = &sA[w*8+32][0];
    ushort_t* dB0 = &sB[w*8][0];
    ushort_t* dB1 = &sB[w*8+32][0];

    // ---- fragment read byte-offsets (with matching XOR swizzle) ----
    int aoff[2][2], boff[2][2];
#pragma unroll
    for (int i=0;i<2;i++)
#pragma unroll
        for (int ks=0;ks<2;ks++){
            int sw = (((ks<<2)|fg) ^ (fr & 7)) << 4;
            aoff[i][ks] = (wu*32 + i*16 + fr)*128 + sw;
            boff[i][ks] = (wl*32 + i*16 + fr)*128 + sw;
        }

    float wloc[T_CNT][M_CNT];
#pragma unroll
    for (int t=0;t<T_CNT;t++)
#pragma unroll
        for (int m=0;m<M_CNT;m++) wloc[t][m] = w32[t*M_CNT+m];

    f32x4 comb[T_CNT][2][2];
#pragma unroll
    for (int t=0;t<T_CNT;t++)
#pragma unroll
        for (int i=0;i<2;i++)
#pragma unroll
            for (int j=0;j<2;j++) comb[t][i][j] = (f32x4){0.f,0.f,0.f,0.f};

#pragma unroll
    for (int m=0;m<M_CNT;m++){
        f32x4 acc[2][2];
#pragma unroll
        for (int i=0;i<2;i++)
#pragma unroll
            for (int j=0;j<2;j++) acc[i][j] = (f32x4){0.f,0.f,0.f,0.f};
#pragma unroll
        for (int kb=0;kb<4;kb++){
            const int koff = (m*4 + kb) * 64;   // elements
            __syncthreads();
            gload16(pA0 + koff, dA0);
            gload16(pA1 + koff, dA1);
            gload16(pB0 + koff, dB0);
            gload16(pB1 + koff, dB1);
            __syncthreads();
#pragma unroll
            for (int ks=0;ks<2;ks++){
                bf16x8 af0 = *(const bf16x8*)((const char*)sA + aoff[0][ks]);
                bf16x8 af1 = *(const bf16x8*)((const char*)sA + aoff[1][ks]);
                bf16x8 bf0 = *(const bf16x8*)((const char*)sB + boff[0][ks]);
                bf16x8 bf1 = *(const bf16x8*)((const char*)sB + boff[1][ks]);
                acc[0][0] = __builtin_amdgcn_mfma_f32_16x16x32_bf16(af0, bf0, acc[0][0], 0, 0, 0);
                acc[0][1] = __builtin_amdgcn_mfma_f32_16x16x32_bf16(af0, bf1, acc[0][1], 0, 0, 0);
                acc[1][0] = __builtin_amdgcn_mfma_f32_16x16x32_bf16(af1, bf0, acc[1][0], 0, 0, 0);
                acc[1][1] = __builtin_amdgcn_mfma_f32_16x16x32_bf16(af1, bf1, acc[1][1], 0, 0, 0);
            }
        }
#pragma unroll
        for (int t=0;t<T_CNT;t++){
            float wm = wloc[t][m];
#pragma unroll
            for (int i=0;i<2;i++)
#pragma unroll
                for (int j=0;j<2;j++){
                    comb[t][i][j][0] += wm*acc[i][j][0];
                    comb[t][i][j][1] += wm*acc[i][j][1];
                    comb[t][i][j][2] += wm*acc[i][j][2];
                    comb[t][i][j][3] += wm*acc[i][j][3];
                }
        }
    }

    // ---- epilogue: LDS transpose per trait, coalesced u16-key stores ----
    for (int t=0;t<T_CNT;t++){
        __syncthreads();
#pragma unroll
        for (int i=0;i<2;i++)
#pragma unroll
            for (int j=0;j<2;j++)
#pragma unroll
                for (int r=0;r<4;r++)
                    sT[wu*32+i*16+fg*4+r][wl*32+j*16+fr] = comb[t][i][j][r];
        __syncthreads();
        {
            int row = tid >> 2;
            int c0  = (tid & 3) * 16;
            ushort_t h[16];
#pragma unroll
            for (int e=0;e<16;e++){
                _Float16 hv = (_Float16)sT[row][c0+e];
                ushort_t b;
                __builtin_memcpy(&b, &hv, 2);
                h[e] = h2key(b);
            }
            size_t base = (((size_t)(uB+row))*T_CNT + t)*LP + l0 + c0;
            *(uint4*)&slabp[base]   = *(const uint4*)&h[0];
            *(uint4*)&slabp[base+8] = *(const uint4*)&h[8];
        }
    }
}

// -------- K3: exact top-KC per (u,t) via 2-level radix select on u16 keys --------
// grid (SLAB, T); block 256. Row cached in LDS; 3 LDS scans, no sorting.
__global__ __launch_bounds__(256) void select_kernel(const ushort_t* __restrict__ slabp,
    int* __restrict__ candIdx, int s)
{
    __shared__ uint4 srow[L_CNT/8];          // 40000 B
    __shared__ uint_t hist[4][256];          // 4096 B
    __shared__ uint_t h1[256], h2[256];      // 2048 B
    __shared__ int  bufc[KC];
    __shared__ uint_t ctr[2];
    __shared__ uint_t shB, shAbove, shK16, shTot;

    const int tid = threadIdx.x;
    const int wid = tid >> 6;
    const int ul = blockIdx.x, t = blockIdx.y;
    const int gu = s*SLAB + ul;
    const uint4* gsrc = (const uint4*)(slabp + ((size_t)ul*T_CNT + t)*LP);

    hist[0][tid]=0; hist[1][tid]=0; hist[2][tid]=0; hist[3][tid]=0;
    if (tid < 2) ctr[tid] = 0;
    __syncthreads();

    // ---- pass 1: global -> LDS copy + hi-byte histogram ----
    for (int i = tid; i < L_CNT/8; i += 256){
        uint4 pk = gsrc[i];
        srow[i] = pk;
        atomicAdd(&hist[wid][(pk.x>>8)&0xFF],1u); atomicAdd(&hist[wid][pk.x>>24],1u);
        atomicAdd(&hist[wid][(pk.y>>8)&0xFF],1u); atomicAdd(&hist[wid][pk.y>>24],1u);
        atomicAdd(&hist[wid][(pk.z>>8)&0xFF],1u); atomicAdd(&hist[wid][pk.z>>24],1u);
        atomicAdd(&hist[wid][(pk.w>>8)&0xFF],1u); atomicAdd(&hist[wid][pk.w>>24],1u);
    }
    __syncthreads();
    h1[tid] = hist[0][tid]+hist[1][tid]+hist[2][tid]+hist[3][tid];
    // inclusive suffix sum over 256 buckets (ping-pong, 8 steps)
    {
        uint_t* src = h1; uint_t* dst = h2;
#pragma unroll
        for (int st=1; st<256; st<<=1){
            __syncthreads();
            dst[tid] = src[tid] + ((tid+st < 256) ? src[tid+st] : 0u);
            uint_t* tmp = src; src = dst; dst = tmp;
        }
        __syncthreads();
        uint_t ge = src[tid];
        uint_t gt = (tid < 255) ? src[tid+1] : 0u;
        if (ge >= (uint_t)KC && gt < (uint_t)KC){ shB = (uint_t)tid; shAbove = gt; }
    }
    __syncthreads();
    const uint_t B = shB, cAb = shAbove;

    // ---- pass 2: low-byte histogram within bucket B ----
    hist[0][tid]=0; hist[1][tid]=0; hist[2][tid]=0; hist[3][tid]=0;
    __syncthreads();
    for (int i = tid; i < L_CNT/8; i += 256){
        uint4 pk = srow[i];
        uint_t k;
        k = pk.x & 0xFFFFu; if ((k>>8)==B) atomicAdd(&hist[wid][k&0xFF],1u);
        k = pk.x >> 16;     if ((k>>8)==B) atomicAdd(&hist[wid][k&0xFF],1u);
        k = pk.y & 0xFFFFu; if ((k>>8)==B) atomicAdd(&hist[wid][k&0xFF],1u);
        k = pk.y >> 16;     if ((k>>8)==B) atomicAdd(&hist[wid][k&0xFF],1u);
        k = pk.z & 0xFFFFu; if ((k>>8)==B) atomicAdd(&hist[wid][k&0xFF],1u);
        k = pk.z >> 16;     if ((k>>8)==B) atomicAdd(&hist[wid][k&0xFF],1u);
        k = pk.w & 0xFFFFu; if ((k>>8)==B) atomicAdd(&hist[wid][k&0xFF],1u);
        k = pk.w >> 16;     if ((k>>8)==B) atomicAdd(&hist[wid][k&0xFF],1u);
    }
    __syncthreads();
    h1[tid] = hist[0][tid]+hist[1][tid]+hist[2][tid]+hist[3][tid];
    {
        uint_t* src = h1; uint_t* dst = h2;
#pragma unroll
        for (int st=1; st<256; st<<=1){
            __syncthreads();
            dst[tid] = src[tid] + ((tid+st < 256) ? src[tid+st] : 0u);
            uint_t* tmp = src; src = dst; dst = tmp;
        }
        __syncthreads();
        uint_t ge = src[tid] + cAb;
        uint_t gt = ((tid < 255) ? src[tid+1] : 0u) + cAb;
        if (ge >= (uint_t)KC && gt < (uint_t)KC){ shK16 = (B<<8) | (uint_t)tid; shTot = gt; }
    }
    __syncthreads();
    const uint_t K16 = shK16, tot = shTot;   // tot = #(key > K16) < KC

    // ---- pass 3: collect above-set + fill with ties ----
    for (int i = tid; i < L_CNT/8; i += 256){
        uint4 pk = srow[i];
        uint_t kk[8];
        kk[0] = pk.x & 0xFFFFu; kk[1] = pk.x >> 16;
        kk[2] = pk.y & 0xFFFFu; kk[3] = pk.y >> 16;
        kk[4] = pk.z & 0xFFFFu; kk[5] = pk.z >> 16;
        kk[6] = pk.w & 0xFFFFu; kk[7] = pk.w >> 16;
#pragma unroll
        for (int e=0;e<8;e++){
            if (kk[e] > K16){
                uint_t slot = atomicAdd(&ctr[0], 1u);
                bufc[slot] = i*8 + e;
            } else if (kk[e] == K16){
                uint_t slot = atomicAdd(&ctr[1], 1u) + tot;
                if (slot < (uint_t)KC) bufc[slot] = i*8 + e;
            }
        }
    }
    __syncthreads();
    if (tid < KC) candIdx[((size_t)gu*T_CNT + t)*KC + tid] = bufc[tid];
}

// -------- K4: f64 rescore, one wave per (u,t,candidate) --------
__global__ __launch_bounds__(256) void rescore_kernel(
    const float* __restrict__ lab, const float* __restrict__ unl,
    const double* __restrict__ w64, const double* __restrict__ invL64,
    const double* __restrict__ invU64, const int* __restrict__ candIdx,
    double* __restrict__ candSim)
{
    int q = blockIdx.x*4 + (threadIdx.x >> 6);      // 0 .. U*T*KC-1
    int lane = threadIdx.x & 63;
    int ut = q >> 4;                                 // u*T + t
    int t = ut % T_CNT;
    int u = ut / T_CNT;
    int idx = candIdx[q];
    double sim = 0.0;
#pragma unroll
    for (int m=0;m<M_CNT;m++){
        float4 a = *(const float4*)&unl[(((size_t)u*M_CNT)+m)*D_CNT + lane*4];
        float4 b = *(const float4*)&lab[(((size_t)idx*M_CNT)+m)*D_CNT + lane*4];
        double d = (double)a.x*b.x + (double)a.y*b.y + (double)a.z*b.z + (double)a.w*b.w;
#pragma unroll
        for (int mm=1;mm<64;mm<<=1) d += dshfl_xor(d, mm);
        sim += w64[t*M_CNT+m] * d * invU64[u*M_CNT+m] * invL64[idx*M_CNT+m];
    }
    if (lane == 0) candSim[q] = sim;
}

// -------- K5: sort 16 candidates per (u,t), emit traits/index outputs --------
__global__ __launch_bounds__(256) void finalize_kernel(
    const double* __restrict__ candSim, const int* __restrict__ candIdx,
    const float* __restrict__ traits,
    float* __restrict__ outTraits, float* __restrict__ outIdx, int* __restrict__ finalIdx)
{
    int id = blockIdx.x*256 + threadIdx.x;
    if (id >= U_CNT*T_CNT) return;
    int t = id % T_CNT;
    double cv[KC]; int ci[KC];
#pragma unroll
    for (int c=0;c<KC;c++){ cv[c] = candSim[(size_t)id*KC + c]; ci[c] = candIdx[(size_t)id*KC + c]; }
#pragma unroll
    for (int i=0;i<KC;i++)
#pragma unroll
        for (int j=0;j<KC-1;j++){
            bool sw = (cv[j] < cv[j+1]) || (cv[j] == cv[j+1] && ci[j] > ci[j+1]);
            if (sw){ double tv=cv[j]; cv[j]=cv[j+1]; cv[j+1]=tv; int ti=ci[j]; ci[j]=ci[j+1]; ci[j+1]=ti; }
        }
#pragma unroll
    for (int k=0;k<K_OUT;k++){
        size_t ob = (size_t)id*K_OUT + k;
        int fi = ci[k];
        outTraits[ob] = traits[(size_t)fi*T_CNT + t];
        outIdx[ob] = (float)fi;
        finalIdx[ob] = fi;
    }
}

// -------- K6: embedding gather --------
__global__ __launch_bounds__(192) void gather_kernel(const float* __restrict__ lab,
    const int* __restrict__ finalIdx, float* __restrict__ outEmb)
{
    int b = blockIdx.x;
    int idx = finalIdx[b];
    const float4* src = (const float4*)(lab + (size_t)idx * (M_CNT*D_CNT));
    float4* dst = (float4*)(outEmb + (size_t)b * (M_CNT*D_CNT));
    dst[threadIdx.x] = src[threadIdx.x];
}

extern "C" void kernel_launch(void* const* d_in, const int* in_sizes, int n_in,
                              void* d_out, int out_size, void* d_ws, size_t ws_size,
                              hipStream_t stream) {
    const float* lab    = (const float*)d_in[0];   // [20000,3,256]
    const float* traits = (const float*)d_in[1];   // [20000,5]
    const float* unl    = (const float*)d_in[2];   // [2048,3,256]
    const float* logits = (const float*)d_in[3];   // [5,3]

    float* out = (float*)d_out;
    float* outEmb = out;                                           // U*T*K*M*D = 62,914,560 f32
    float* outTr  = out + (size_t)U_CNT*T_CNT*K_OUT*M_CNT*D_CNT;
    float* outIx  = outTr + (size_t)U_CNT*T_CNT*K_OUT;

    char* wsb = (char*)d_ws;
    size_t off = 0;
    auto take = [&](size_t bytes)->void*{
        void* p = wsb + off;
        off = (off + bytes + 255) & ~(size_t)255;
        return p;
    };
    double* invL64 = (double*)take((size_t)LROWS*sizeof(double));
    double* invU64 = (double*)take((size_t)UROWS*sizeof(double));
    float*  w32    = (float*) take(T_CNT*M_CNT*sizeof(float));
    double* w64    = (double*)take(T_CNT*M_CNT*sizeof(double));
    int*    candIdx= (int*)   take((size_t)U_CNT*T_CNT*KC*sizeof(int));
    double* candSim= (double*)take((size_t)U_CNT*T_CNT*KC*sizeof(double));
    int*    finalIdx=(int*)   take((size_t)U_CNT*T_CNT*K_OUT*sizeof(int));
    ushort_t* labN = (ushort_t*)take((size_t)LROWS*D_CNT*sizeof(ushort_t)); // 30.7 MB
    ushort_t* unlN = (ushort_t*)take((size_t)UROWS*D_CNT*sizeof(ushort_t)); // 3.15 MB

    // key slab lives in d_out's embedding region (written only by final gather):
    // SLAB*T_CNT*LP u16 = 205.1 MB <= 251.6 MB region. Fully consumed before gather.
    ushort_t* slabK = (ushort_t*)outEmb;

    weights_kernel<<<1, 64, 0, stream>>>(logits, w32, w64);
    {
        int nrow = LROWS + UROWS;
        prep_kernel<<<(nrow+3)/4, 256, 0, stream>>>(lab, unl, invL64, invU64, labN, unlN);
    }
    const int LTILES = (L_CNT + 63)/64;              // 313
    for (int s = 0; s < NSLAB; ++s){
        sim_kernel<<<dim3(SLAB/64, LTILES), 256, 0, stream>>>(labN, unlN, w32, slabK, s);
        select_kernel<<<dim3(SLAB, T_CNT), 256, 0, stream>>>(slabK, candIdx, s);
    }
    rescore_kernel<<<(U_CNT*T_CNT*KC)/4, 256, 0, stream>>>(lab, unl, w64, invL64, invU64, candIdx, candSim);
    finalize_kernel<<<(U_CNT*T_CNT + 255)/256, 256, 0, stream>>>(candSim, candIdx, traits, outTr, outIx, finalIdx);
    gather_kernel<<<U_CNT*T_CNT*K_OUT, 192, 0, stream>>>(lab, finalIdx, outEmb);
}